// Round 8
// baseline (290.037 us; speedup 1.0000x reference)
//
#include <hip/hip_runtime.h>

// Causal SDPA: B=4,H=16,S=2048,D=64, fp32 in/out.
// Flash attention, bf16 mfma 16x16x32, swapped QK^T (S^T = K.Q) with permuted
// K staging so P feeds PV directly. KVBLK=64, exp2-domain softmax,
// XOR-swizzled 16B-cell LDS (conflict-free), double-buffered with
// prefetch-to-regs, 1 barrier/iter, defer-rescale, setprio, MFMA row-sum.
// Round 8: 512-thread blocks (8 waves x 32 q-rows = 256 q-rows/block) so one
// staged K/V tile feeds 2x the MFMA (fixes round-7's doubled staging);
// grid 512 -> 2 blocks/CU = 4 waves/SIMD; blocks i and i+256 hold q-tiles
// with uniform combined work (36 iters) for CU-level balance.

#define SEQ 2048
#define HD  64

typedef __attribute__((ext_vector_type(8))) short short8;
typedef __attribute__((ext_vector_type(4))) float f32x4;
typedef __attribute__((ext_vector_type(2))) float f32x2;
typedef __attribute__((ext_vector_type(2))) __bf16 bf16x2;

__device__ __forceinline__ unsigned pk2(float lo, float hi) {
    union { bf16x2 v; unsigned u; } r;
    r.v = __builtin_convertvector((f32x2){lo, hi}, bf16x2);
    return r.u;
}

// Per buffer: K tile 8192 B + V^T tile 8192 B. Cells are 16 B (8 bf16),
// XOR-swizzled: cell addr = (row*8 + (unit ^ (row&7))) * 16.
__global__ __launch_bounds__(512, 4) void sdpa_kernel(
    const float* __restrict__ Q, const float* __restrict__ K,
    const float* __restrict__ V, float* __restrict__ O)
{
    __shared__ __align__(16) char smraw[32768];

    const int bx = blockIdx.x;
    const int bh = bx & 63;
    const int qt = (bx < 256) ? (7 - (bx >> 6)) : ((bx - 256) >> 6);
    const int qbase = qt * 256;           // 256 q rows per block

    const int tid  = threadIdx.x;
    const int lane = tid & 63;
    const int w    = tid >> 6;            // 0..7
    const int g    = lane >> 4;
    const int r16  = lane & 15;
    const int wq   = qbase + w * 32;      // wave's 32 q rows

    const size_t base = (size_t)bh * (SEQ * HD);

    // staging thread assignments (512 threads)
    const int k_kvo = tid >> 3;                      // K row 0..63
    const int k_u   = tid & 7;                       // cell unit
    const int k_o   = k_kvo & 31;
    const int k_row = (k_kvo & 32) + 16 * ((k_o >> 2) & 1) + 4 * (k_o >> 3) + (k_o & 3);
    const int v_kv0 = (tid & 31) * 2;                // kv pair
    const int v_db  = (tid >> 5) * 4;                // 4 d rows

    // ones bf16 fragment for MFMA row-sum of P
    short8 ones;
    { union { short8 s; unsigned u[4]; } o_;
      o_.u[0] = o_.u[1] = o_.u[2] = o_.u[3] = 0x3F803F80u; ones = o_.s; }

    // prefetch registers (held across compute)
    f32x4 ka0, ka1, va0, vb0;

    auto LOADT = [&](int kvbase) {
        const float* kp = K + base + (size_t)(kvbase + k_kvo) * HD + k_u * 8;
        ka0 = *(const f32x4*)(kp + 0);
        ka1 = *(const f32x4*)(kp + 4);
        const float* vp = V + base + (size_t)(kvbase + v_kv0) * HD + v_db;
        va0 = *(const f32x4*)(vp + 0);
        vb0 = *(const f32x4*)(vp + HD);
    };
    auto WRITET = [&](int b) {
        char* Kl = smraw + b * 16384;
        char* Vl = Kl + 8192;
        union { short8 s; unsigned u[4]; } c0;
        c0.u[0] = pk2(ka0[0], ka0[1]); c0.u[1] = pk2(ka0[2], ka0[3]);
        c0.u[2] = pk2(ka1[0], ka1[1]); c0.u[3] = pk2(ka1[2], ka1[3]);
        *(short8*)(Kl + ((k_row * 8 + (k_u ^ (k_row & 7))) << 4)) = c0.s;
        const int u  = v_kv0 >> 3;
        const int wo = (v_kv0 & 7) * 2;
        #pragma unroll
        for (int i = 0; i < 4; ++i) {
            const int d = v_db + i;
            *(unsigned*)(Vl + ((d * 8 + (u ^ (d & 7))) << 4) + wo) = pk2(va0[i], vb0[i]);
        }
    };

    const float SC = 0.18033688011112042f;   // 0.125 * log2(e)

    // ---- Q fragments (2 subtiles x 2 k-chunks) ----
    short8 qf[2][2];
    #pragma unroll
    for (int qs = 0; qs < 2; ++qs) {
        const float* qp = Q + base + (size_t)(wq + qs * 16 + r16) * HD + 8 * g;
        #pragma unroll
        for (int c = 0; c < 2; ++c) {
            f32x4 a = *(const f32x4*)(qp + c * 32);
            f32x4 b = *(const f32x4*)(qp + c * 32 + 4);
            union { short8 s; unsigned u[4]; } t;
            t.u[0] = pk2(a[0] * SC, a[1] * SC);
            t.u[1] = pk2(a[2] * SC, a[3] * SC);
            t.u[2] = pk2(b[0] * SC, b[1] * SC);
            t.u[3] = pk2(b[2] * SC, b[3] * SC);
            qf[qs][c] = t.s;
        }
    }

    f32x4 oacc[2][4] = {};
    f32x4 lacc[2] = {};
    float mrun[2] = {-1e30f, -1e30f};

    const int nkvb = (qbase + 256) >> 6;

    LOADT(0);
    WRITET(0);
    __syncthreads();

    for (int kvb = 0; kvb < nkvb; ++kvb) {
        const int kvbase = kvb << 6;
        const int buf = kvb & 1;
        const bool more = (kvb + 1 < nkvb);

        if (more) LOADT((kvb + 1) << 6);   // issue prefetch loads early

        if (kvbase <= wq + 31) {           // wave-uniform causal activity
            const char* Kl = smraw + buf * 16384;
            const char* Vl = Kl + 8192;

            // ---- QK^T (shared K-fragment reads across q-subtiles) ----
            f32x4 sa[2][2][2];
            #pragma unroll
            for (int qs = 0; qs < 2; ++qs)
                #pragma unroll
                for (int c2 = 0; c2 < 2; ++c2)
                    #pragma unroll
                    for (int t = 0; t < 2; ++t)
                        sa[qs][c2][t] = (f32x4){0.f, 0.f, 0.f, 0.f};
            __builtin_amdgcn_s_setprio(1);
            #pragma unroll
            for (int c2 = 0; c2 < 2; ++c2)
                #pragma unroll
                for (int t = 0; t < 2; ++t)
                    #pragma unroll
                    for (int c = 0; c < 2; ++c) {
                        const int row = c2 * 32 + t * 16 + r16;
                        short8 kf = *(const short8*)(Kl + ((row * 8 + ((4 * c + g) ^ (row & 7))) << 4));
                        sa[0][c2][t] = __builtin_amdgcn_mfma_f32_16x16x32_bf16(kf, qf[0][c], sa[0][c2][t], 0, 0, 0);
                        sa[1][c2][t] = __builtin_amdgcn_mfma_f32_16x16x32_bf16(kf, qf[1][c], sa[1][c2][t], 0, 0, 0);
                    }
            __builtin_amdgcn_s_setprio(0);

            // ---- causal mask (diagonal region only) ----
            #pragma unroll
            for (int qs = 0; qs < 2; ++qs) {
                const int q0 = wq + qs * 16;
                if (kvbase + 63 > q0) {
                    const int qrow = q0 + r16;
                    #pragma unroll
                    for (int c2 = 0; c2 < 2; ++c2)
                        #pragma unroll
                        for (int t = 0; t < 2; ++t)
                            #pragma unroll
                            for (int r = 0; r < 4; ++r) {
                                const int kv = kvbase + c2 * 32 + 8 * g + 4 * t + r;
                                if (kv > qrow) sa[qs][c2][t][r] = -1e30f;
                            }
                }
            }

            // ---- stats + defer-rescale (exp2 domain, THR=8) ----
            float mnew[2];
            #pragma unroll
            for (int qs = 0; qs < 2; ++qs) {
                float mloc = sa[qs][0][0][0];
                #pragma unroll
                for (int c2 = 0; c2 < 2; ++c2)
                    #pragma unroll
                    for (int t = 0; t < 2; ++t)
                        #pragma unroll
                        for (int r = 0; r < 4; ++r)
                            mloc = fmaxf(mloc, sa[qs][c2][t][r]);
                mloc = fmaxf(mloc, __shfl_xor(mloc, 16));
                mloc = fmaxf(mloc, __shfl_xor(mloc, 32));
                mnew[qs] = fmaxf(mrun[qs], mloc);
            }
            if (!__all((mnew[0] - mrun[0] <= 8.0f) && (mnew[1] - mrun[1] <= 8.0f))) {
                #pragma unroll
                for (int qs = 0; qs < 2; ++qs) {
                    const float alpha = __builtin_amdgcn_exp2f(mrun[qs] - mnew[qs]);
                    mrun[qs] = mnew[qs];
                    lacc[qs][0] *= alpha;      // only [0] is ever read
                    #pragma unroll
                    for (int dt = 0; dt < 4; ++dt) oacc[qs][dt] *= alpha;
                }
            }
            #pragma unroll
            for (int qs = 0; qs < 2; ++qs)
                #pragma unroll
                for (int c2 = 0; c2 < 2; ++c2)
                    #pragma unroll
                    for (int t = 0; t < 2; ++t)
                        #pragma unroll
                        for (int r = 0; r < 4; ++r)
                            sa[qs][c2][t][r] =
                                __builtin_amdgcn_exp2f(sa[qs][c2][t][r] - mrun[qs]);

            // ---- PV: O^T += V^T . P ; l += ones . P (MFMA row-sum) ----
            #pragma unroll
            for (int c2 = 0; c2 < 2; ++c2) {
                union { short8 s; unsigned u[4]; } pf0, pf1;
                pf0.u[0] = pk2(sa[0][c2][0][0], sa[0][c2][0][1]);
                pf0.u[1] = pk2(sa[0][c2][0][2], sa[0][c2][0][3]);
                pf0.u[2] = pk2(sa[0][c2][1][0], sa[0][c2][1][1]);
                pf0.u[3] = pk2(sa[0][c2][1][2], sa[0][c2][1][3]);
                pf1.u[0] = pk2(sa[1][c2][0][0], sa[1][c2][0][1]);
                pf1.u[1] = pk2(sa[1][c2][0][2], sa[1][c2][0][3]);
                pf1.u[2] = pk2(sa[1][c2][1][0], sa[1][c2][1][1]);
                pf1.u[3] = pk2(sa[1][c2][1][2], sa[1][c2][1][3]);
                __builtin_amdgcn_s_setprio(1);
                lacc[0] = __builtin_amdgcn_mfma_f32_16x16x32_bf16(ones, pf0.s, lacc[0], 0, 0, 0);
                lacc[1] = __builtin_amdgcn_mfma_f32_16x16x32_bf16(ones, pf1.s, lacc[1], 0, 0, 0);
                #pragma unroll
                for (int dt = 0; dt < 4; ++dt) {
                    const int row = dt * 16 + r16;
                    short8 vf = *(const short8*)(Vl + ((row * 8 + ((c2 * 4 + g) ^ (row & 7))) << 4));
                    oacc[0][dt] = __builtin_amdgcn_mfma_f32_16x16x32_bf16(vf, pf0.s, oacc[0][dt], 0, 0, 0);
                    oacc[1][dt] = __builtin_amdgcn_mfma_f32_16x16x32_bf16(vf, pf1.s, oacc[1][dt], 0, 0, 0);
                }
                __builtin_amdgcn_s_setprio(0);
            }
        }

        if (more) {
            WRITET(buf ^ 1);               // cvt+write prefetched tile
            __syncthreads();
        }
    }

    // ---- epilogue: direct coalesced stores from the accumulator ----
    #pragma unroll
    for (int qs = 0; qs < 2; ++qs) {
        const float inv = 1.0f / lacc[qs][0];
        float* op = O + base + (size_t)(wq + qs * 16 + r16) * HD + 4 * g;
        #pragma unroll
        for (int dt = 0; dt < 4; ++dt) {
            f32x4 vv = oacc[qs][dt] * inv;
            *(f32x4*)(op + dt * 16) = vv;
        }
    }
}

extern "C" void kernel_launch(void* const* d_in, const int* in_sizes, int n_in,
                              void* d_out, int out_size, void* d_ws, size_t ws_size,
                              hipStream_t stream) {
    (void)in_sizes; (void)n_in; (void)out_size; (void)d_ws; (void)ws_size;
    const float* q = (const float*)d_in[0];
    const float* k = (const float*)d_in[1];
    const float* v = (const float*)d_in[2];
    float* o = (float*)d_out;
    sdpa_kernel<<<dim3(512), dim3(512), 0, stream>>>(q, k, v, o);
}